// Round 2
// baseline (306.289 us; speedup 1.0000x reference)
//
#include <hip/hip_runtime.h>
#include <hip/hip_bf16.h>

// Word2Vec fused loss. M=4086 centers (pad 4096), V=32000, D=128.
// exp2/log2 domain: A holds bf16(ctx_mean*log2e); per-row S = sum_v 2^(A.Wb_v);
// loss = sum_i [ LN2*log2(S_i) - tgt_i ].
//
// R6: k_gemm rewritten: NO LDS, NO barriers in the main loop. K=128 A-frags are
// register-resident (a[2][4], 32 VGPR). Each wave loads its B-frags straight
// global->VGPR (8x dwordx4/step, perfectly coalesced, tile is L1-resident for
// the 3 sibling waves), 2-deep explicit register double-buffer (bA/bB, static
// indices only) so step t+1's loads hide under step t's MFMA+exp2.
// Rationale (R1 post-mortem): R5 spilled a[4][4] to scratch (VGPR=60,
// WRITE_SIZE 5.16MB = exact spill footprint) -> 173us all-idle. The LDS/barrier
// path also paid a vmcnt(0) drain + 2M bank-conflict cycles per dispatch.
// Wb is now PLAIN row-major bf16 (swizzle removed - it was LDS-only).
// k_fin stays merged into k_gemm via last-block ticket (agent-scope atomics).

#define NCTR 4086
#define WIN 5
#define VOC 32000
#define DIM 128
#define MPAD 4096
#define LOG2E 1.44269504088896340736f
#define LN2 0.69314718055994530942f

#define MT 128
#define NT 32
#define SSTR 40
#define TSTEP 25
#define NBLK (32 * SSTR)
#define GSTEP (SSTR * NT * 16)   // step stride in bf16x8 chunk units (=20480)

typedef __attribute__((ext_vector_type(8))) __bf16 bf16x8;
typedef __attribute__((ext_vector_type(4))) float f32x4;

// ws layout (bytes):
//   [0,        8192000)  Wb : bf16 VOC*DIM plain row-major
//   [8192000,  9240576)  A  : bf16 MPAD*DIM plain row-major (log2e-scaled)
//   [9240576,  9256960)  expsum : float MPAD
//   [9256960,  9273344)  tgt    : float MPAD
//   [9273344,  9273348)  cnt    : uint ticket counter (zeroed by k_setup)
#define WS_A      8192000
#define WS_EXPSUM 9240576
#define WS_TGT    9256960
#define WS_CNT    9273344

#define NWCONV 2000   // VOC*16 chunk-units / 256
#define NCTXB  2048   // MPAD/2

#if __has_builtin(__builtin_amdgcn_exp2f)
#define EXP2(x) __builtin_amdgcn_exp2f(x)
#else
#define EXP2(x) exp2f(x)
#endif

__global__ __launch_bounds__(256) void k_setup(const int* __restrict__ tokens,
                                               const float* __restrict__ emb,
                                               const float* __restrict__ W,
                                               __bf16* __restrict__ Wb,
                                               __bf16* __restrict__ A,
                                               float* __restrict__ tgt,
                                               float* __restrict__ expsum,
                                               unsigned* __restrict__ cnt) {
    if (blockIdx.x < NWCONV) {
        // W fp32 -> Wb bf16, 8 elems (one 16-B chunk) per thread, plain layout.
        int id = blockIdx.x * 256 + threadIdx.x;   // (r, c) unit
        int r = id >> 4, c = id & 15;
        const f32x4* src = (const f32x4*)(W + (size_t)r * DIM + c * 8);
        f32x4 v0 = src[0], v1 = src[1];
        bf16x8 o;
        o[0] = (__bf16)v0.x; o[1] = (__bf16)v0.y; o[2] = (__bf16)v0.z; o[3] = (__bf16)v0.w;
        o[4] = (__bf16)v1.x; o[5] = (__bf16)v1.y; o[6] = (__bf16)v1.z; o[7] = (__bf16)v1.w;
        ((bf16x8*)Wb)[r * 16 + c] = o;
        return;
    }
    if (blockIdx.x == NWCONV && threadIdx.x == 0) *cnt = 0u;
    // ctx part: 2 rows per block; threads [0,128) row0, [128,256) row1
    int i = (blockIdx.x - NWCONV) * 2 + (threadIdx.x >> 7);
    int d = threadIdx.x & 127;
    int half = threadIdx.x >> 7;
    if (d == 0) expsum[i] = 0.0f;
    __shared__ float red[4];
    if (i >= NCTR) {
        A[i * DIM + d] = (__bf16)0.0f;
        if (d == 0) tgt[i] = 0.0f;
        return;
    }
    int p = i + WIN;
    float s = 0.0f;
#pragma unroll
    for (int o = 1; o <= WIN; ++o) {
        s += emb[(long)tokens[p - o] * DIM + d];
        s += emb[(long)tokens[p + o] * DIM + d];
    }
    float m = s * 0.1f;
    A[i * DIM + d] = (__bf16)(m * LOG2E);
    float prod = m * W[(long)tokens[p] * DIM + d];   // natural-log-domain target logit
#pragma unroll
    for (int off = 32; off; off >>= 1) prod += __shfl_down(prod, off);
    if ((threadIdx.x & 63) == 0) red[threadIdx.x >> 6] = prod;
    __syncthreads();
    if (d == 0) tgt[i] = red[half * 2] + red[half * 2 + 1];
}

// grid (32, 40): blockIdx.x = M-tile, blockIdx.y = N-stream.
// Wave wv owns M-rows [m0+wv*32, +32); all waves cover the full 32-col step.
// Per step: 8 global_load_dwordx4 (rows lrow / lrow+16, chunk kb*4+quad),
// 16 MFMA, 16 exp2-accum. No LDS, no __syncthreads in the loop.
__global__ __launch_bounds__(256) void k_gemm(const __bf16* __restrict__ A,
                                              const __bf16* __restrict__ Wb,
                                              float* __restrict__ expsum,
                                              const float* __restrict__ tgt,
                                              unsigned* __restrict__ cnt,
                                              float* __restrict__ out) {
    __shared__ float fred[4];
    __shared__ int sdone;
    const int tid  = threadIdx.x;
    const int lane = tid & 63;
    const int wv   = tid >> 6;
    const int lrow = lane & 15;
    const int quad = lane >> 4;
    const int m0   = blockIdx.x * MT;
    const int sid  = blockIdx.y;

    // A-frags: rows m0 + wv*32 + ms*16 + lrow, chunk kb*4+quad
    bf16x8 a[2][4];
    {
        const bf16x8* Ap = (const bf16x8*)A + (size_t)(m0 + wv * 32 + lrow) * 16 + quad;
#pragma unroll
        for (int ms = 0; ms < 2; ++ms)
#pragma unroll
            for (int kb = 0; kb < 4; ++kb)
                a[ms][kb] = Ap[ms * 256 + kb * 4];
    }

    float run[2][4];
#pragma unroll
    for (int ms = 0; ms < 2; ++ms)
#pragma unroll
        for (int r = 0; r < 4; ++r) run[ms][r] = 0.0f;

    // B base: step t covers Wb rows (t*SSTR + sid)*NT .. +NT. Lane reads row
    // lrow (lo half) / lrow+16 (hi half), 16-B chunk kb*4+quad.
    const bf16x8* Bp = (const bf16x8*)Wb + (size_t)(sid * NT + lrow) * 16 + quad;

    const f32x4 z = {0.0f, 0.0f, 0.0f, 0.0f};
    bf16x8 bA[8], bB[8];

#define LOADB(dst, t) do {                                                    \
        const bf16x8* p_ = Bp + (size_t)(t) * GSTEP;                          \
        dst[0] = p_[0];   dst[1] = p_[4];   dst[2] = p_[8];   dst[3] = p_[12];\
        dst[4] = p_[256]; dst[5] = p_[260]; dst[6] = p_[264]; dst[7] = p_[268];\
    } while (0)

#define COMPUTE(bs) do {                                                      \
        f32x4 acc00 = z, acc01 = z, acc10 = z, acc11 = z;                     \
        _Pragma("unroll")                                                     \
        for (int kb = 0; kb < 4; ++kb) {                                      \
            acc00 = __builtin_amdgcn_mfma_f32_16x16x32_bf16(a[0][kb], bs[kb],     acc00, 0, 0, 0); \
            acc01 = __builtin_amdgcn_mfma_f32_16x16x32_bf16(a[0][kb], bs[4 + kb], acc01, 0, 0, 0); \
            acc10 = __builtin_amdgcn_mfma_f32_16x16x32_bf16(a[1][kb], bs[kb],     acc10, 0, 0, 0); \
            acc11 = __builtin_amdgcn_mfma_f32_16x16x32_bf16(a[1][kb], bs[4 + kb], acc11, 0, 0, 0); \
        }                                                                     \
        _Pragma("unroll")                                                     \
        for (int r = 0; r < 4; ++r) {                                         \
            run[0][r] += EXP2(acc00[r]) + EXP2(acc01[r]);                     \
            run[1][r] += EXP2(acc10[r]) + EXP2(acc11[r]);                     \
        }                                                                     \
    } while (0)

    LOADB(bA, 0);
    // 2-deep register pipeline over 25 steps: steps 0..23 in the loop, 24 after.
    for (int t = 0; t < TSTEP - 1; t += 2) {
        LOADB(bB, t + 1);
        COMPUTE(bA);
        if (t + 2 < TSTEP) LOADB(bA, t + 2);
        COMPUTE(bB);
    }
    COMPUTE(bA);   // step 24

#undef LOADB
#undef COMPUTE

    // D layout: row m = quad*4 + r (within 16-tile), col = lrow. Reduce over the
    // 16 col-lanes (lane bits 0..3), then one atomic per row per wave.
#pragma unroll
    for (int ms = 0; ms < 2; ++ms)
#pragma unroll
        for (int r = 0; r < 4; ++r) {
            float v = run[ms][r];
            v += __shfl_xor(v, 1);
            v += __shfl_xor(v, 2);
            v += __shfl_xor(v, 4);
            v += __shfl_xor(v, 8);
            if (lrow == 0)
                atomicAdd(&expsum[m0 + wv * 32 + ms * 16 + quad * 4 + r], v);
        }

    // last-block finalization (replaces k_fin): ticket after this block's atomics.
    __threadfence();
    __syncthreads();
    if (tid == 0) {
        unsigned tk = __hip_atomic_fetch_add(cnt, 1u, __ATOMIC_ACQ_REL, __HIP_MEMORY_SCOPE_AGENT);
        sdone = (tk == NBLK - 1);
    }
    __syncthreads();
    if (!sdone) return;

    float s = 0.0f;
#pragma unroll
    for (int j = 0; j < 16; ++j) {
        int idx = tid * 16 + j;   // 256*16 = 4096
        float e = __hip_atomic_load(&expsum[idx], __ATOMIC_RELAXED, __HIP_MEMORY_SCOPE_AGENT);
        if (idx < NCTR) s += LN2 * __log2f(e) - tgt[idx];
    }
#pragma unroll
    for (int off = 32; off; off >>= 1) s += __shfl_down(s, off);
    if ((tid & 63) == 0) fred[tid >> 6] = s;
    __syncthreads();
    if (tid == 0) out[0] = fred[0] + fred[1] + fred[2] + fred[3];
}

extern "C" void kernel_launch(void* const* d_in, const int* in_sizes, int n_in,
                              void* d_out, int out_size, void* d_ws, size_t ws_size,
                              hipStream_t stream) {
    const int*   tokens = (const int*)d_in[0];
    const float* emb    = (const float*)d_in[1];
    const float* W      = (const float*)d_in[2];
    float* out = (float*)d_out;
    char* ws = (char*)d_ws;
    __bf16*   Wb     = (__bf16*)ws;
    __bf16*   A      = (__bf16*)(ws + WS_A);
    float*    expsum = (float*)(ws + WS_EXPSUM);
    float*    tgt    = (float*)(ws + WS_TGT);
    unsigned* cnt    = (unsigned*)(ws + WS_CNT);

    k_setup<<<dim3(NWCONV + NCTXB), 256, 0, stream>>>(tokens, emb, W, Wb, A, tgt, expsum, cnt);
    k_gemm <<<dim3(32, SSTR), 256, 0, stream>>>(A, Wb, expsum, tgt, cnt, out);   // 1280 blocks
}

// Round 3
// 244.463 us; speedup vs baseline: 1.2529x; 1.2529x over previous
//
#include <hip/hip_runtime.h>
#include <hip/hip_bf16.h>

// Word2Vec fused loss. M=4086 centers (pad 4096), V=32000, D=128.
// exp2/log2 domain: A holds bf16(ctx_mean*log2e); per-row S = sum_v 2^(A.Wb_v);
// loss = sum_i [ LN2*log2(S_i) - tgt_i ].
//
// R7 = R0's proven k_gemm register structure (a[2][4], 4 waves x 32Mx32N, LDS
// staging via global_load_lds w16, XOR-swizzle baked into Wb) -- R1/R2 post-
// mortem: any bigger register plan spills (VGPR=60/80, WRITE_SIZE = spill
// footprint, all pipes <8%). Changes vs R0, both register-neutral:
//  1) T4 counted-vmcnt pipeline: 3 LDS buffers, stage t+2 each step,
//     asm s_waitcnt vmcnt(2) + raw s_barrier instead of __syncthreads()
//     (which drains vmcnt(0) every step = the m233 2-phase stall).
//     Last step peeled with vmcnt(0). No register growth, +8KB LDS.
//  2) k_fin merged into k_gemm via last-block ticket (verified in R1/R2).

#define NCTR 4086
#define WIN 5
#define VOC 32000
#define DIM 128
#define MPAD 4096
#define LOG2E 1.44269504088896340736f
#define LN2 0.69314718055994530942f

#define MT 128
#define NT 32
#define SSTR 40
#define TSTEP 25
#define NBLK (32 * SSTR)
#define GSTEP_E (SSTR * NT * DIM)   // step stride in bf16 elems (=163840)

typedef __attribute__((ext_vector_type(8))) __bf16 bf16x8;
typedef __attribute__((ext_vector_type(4))) float f32x4;

// ws layout (bytes):
//   [0,        8192000)  Wb : bf16 VOC*DIM, XOR-swizzled chunks within each row
//   [8192000,  9240576)  A  : bf16 MPAD*DIM plain row-major (log2e-scaled)
//   [9240576,  9256960)  expsum : float MPAD
//   [9256960,  9273344)  tgt    : float MPAD
//   [9273344,  9273348)  cnt    : uint ticket counter (zeroed by k_setup)
#define WS_A      8192000
#define WS_EXPSUM 9240576
#define WS_TGT    9256960
#define WS_CNT    9273344

#define NWCONV 2000   // VOC*16 chunk-units / 256
#define NCTXB  2048   // MPAD/2

#if __has_builtin(__builtin_amdgcn_exp2f)
#define EXP2(x) __builtin_amdgcn_exp2f(x)
#else
#define EXP2(x) exp2f(x)
#endif

#define GLOAD16(g, l) __builtin_amdgcn_global_load_lds(                         \
    (const __attribute__((address_space(1))) void*)(g),                         \
    (__attribute__((address_space(3))) void*)(l), 16, 0, 0)

__global__ __launch_bounds__(256) void k_setup(const int* __restrict__ tokens,
                                               const float* __restrict__ emb,
                                               const float* __restrict__ W,
                                               __bf16* __restrict__ Wb,
                                               __bf16* __restrict__ A,
                                               float* __restrict__ tgt,
                                               float* __restrict__ expsum,
                                               unsigned* __restrict__ cnt) {
    if (blockIdx.x < NWCONV) {
        // W fp32 -> Wb bf16, 8 elems (one 16-B chunk) per thread, XOR-swizzled:
        // chunk c of row r lands at chunk position c ^ (r & 7).
        int id = blockIdx.x * 256 + threadIdx.x;   // (r, c) unit
        int r = id >> 4, c = id & 15;
        const f32x4* src = (const f32x4*)(W + (size_t)r * DIM + c * 8);
        f32x4 v0 = src[0], v1 = src[1];
        bf16x8 o;
        o[0] = (__bf16)v0.x; o[1] = (__bf16)v0.y; o[2] = (__bf16)v0.z; o[3] = (__bf16)v0.w;
        o[4] = (__bf16)v1.x; o[5] = (__bf16)v1.y; o[6] = (__bf16)v1.z; o[7] = (__bf16)v1.w;
        ((bf16x8*)Wb)[r * 16 + (c ^ (r & 7))] = o;
        return;
    }
    if (blockIdx.x == NWCONV && threadIdx.x == 0) *cnt = 0u;
    // ctx part: 2 rows per block; threads [0,128) row0, [128,256) row1
    int i = (blockIdx.x - NWCONV) * 2 + (threadIdx.x >> 7);
    int d = threadIdx.x & 127;
    int half = threadIdx.x >> 7;
    if (d == 0) expsum[i] = 0.0f;
    __shared__ float red[4];
    if (i >= NCTR) {
        A[i * DIM + d] = (__bf16)0.0f;
        if (d == 0) tgt[i] = 0.0f;
        return;
    }
    int p = i + WIN;
    float s = 0.0f;
#pragma unroll
    for (int o = 1; o <= WIN; ++o) {
        s += emb[(long)tokens[p - o] * DIM + d];
        s += emb[(long)tokens[p + o] * DIM + d];
    }
    float m = s * 0.1f;
    A[i * DIM + d] = (__bf16)(m * LOG2E);
    float prod = m * W[(long)tokens[p] * DIM + d];   // natural-log-domain target logit
#pragma unroll
    for (int off = 32; off; off >>= 1) prod += __shfl_down(prod, off);
    if ((threadIdx.x & 63) == 0) red[threadIdx.x >> 6] = prod;
    __syncthreads();
    if (d == 0) tgt[i] = red[half * 2] + red[half * 2 + 1];
}

// grid (32, 40): blockIdx.x = M-tile, blockIdx.y = N-stream.
__global__ __launch_bounds__(256) void k_gemm(const __bf16* __restrict__ A,
                                              const __bf16* __restrict__ Wb,
                                              float* __restrict__ expsum,
                                              const float* __restrict__ tgt,
                                              unsigned* __restrict__ cnt,
                                              float* __restrict__ out) {
    __shared__ __align__(16) __bf16 lds[3][NT * DIM];   // 3 x 8 KB
    __shared__ float fred[4];
    __shared__ int sdone;
    const int tid  = threadIdx.x;
    const int lane = tid & 63;
    const int wv   = tid >> 6;
    const int lrow = lane & 15;
    const int quad = lane >> 4;
    const int m0   = blockIdx.x * MT;
    const int sid  = blockIdx.y;

    // A-frags: rows m0 + wv*32 + ms*16 + lrow, chunk kb*4+quad (plain layout)
    bf16x8 a[2][4];
    {
        const bf16x8* Ap = (const bf16x8*)A + (size_t)(m0 + wv * 32 + lrow) * 16 + quad;
#pragma unroll
        for (int ms = 0; ms < 2; ++ms)
#pragma unroll
            for (int kb = 0; kb < 4; ++kb)
                a[ms][kb] = Ap[ms * 256 + kb * 4];
    }

    float run[2][4];
#pragma unroll
    for (int ms = 0; ms < 2; ++ms)
#pragma unroll
        for (int r = 0; r < 4; ++r) run[ms][r] = 0.0f;

    // staging: step t covers Wb rows (t*SSTR + sid)*NT .. +NT (8 KB contiguous,
    // already swizzled in Wb). Wave wv copies its contiguous 2-KB slice with
    // TWO width-16 global_load_lds (each: 64 lanes x 16 B, deposit base+lane*16).
    const __bf16* gbase = Wb + (size_t)sid * NT * DIM + (size_t)wv * 1024 + (size_t)lane * 8;

#define STAGE(tt, bb) do {                                                    \
        const __bf16* g_ = gbase + (size_t)(tt) * GSTEP_E;                    \
        GLOAD16(g_,       &lds[bb][wv * 1024]);                               \
        GLOAD16(g_ + 512, &lds[bb][wv * 1024 + 512]);                         \
    } while (0)

#define COMPUTE(bb) do {                                                      \
        f32x4 acc[2][2];                                                      \
        const f32x4 z = {0.0f, 0.0f, 0.0f, 0.0f};                             \
        _Pragma("unroll")                                                     \
        for (int ms = 0; ms < 2; ++ms) { acc[ms][0] = z; acc[ms][1] = z; }    \
        _Pragma("unroll")                                                     \
        for (int kb = 0; kb < 4; ++kb) {                                      \
            const int cs = (kb * 4 + quad) ^ (lrow & 7);                      \
            bf16x8 b0 = *(const bf16x8*)&lds[bb][(lrow * 16 + cs) * 8];       \
            bf16x8 b1 = *(const bf16x8*)&lds[bb][((16 + lrow) * 16 + cs) * 8];\
            _Pragma("unroll")                                                 \
            for (int ms = 0; ms < 2; ++ms) {                                  \
                acc[ms][0] = __builtin_amdgcn_mfma_f32_16x16x32_bf16(a[ms][kb], b0, acc[ms][0], 0, 0, 0); \
                acc[ms][1] = __builtin_amdgcn_mfma_f32_16x16x32_bf16(a[ms][kb], b1, acc[ms][1], 0, 0, 0); \
            }                                                                 \
        }                                                                     \
        _Pragma("unroll")                                                     \
        for (int ms = 0; ms < 2; ++ms)                                        \
            _Pragma("unroll")                                                 \
            for (int r = 0; r < 4; ++r)                                       \
                run[ms][r] += EXP2(acc[ms][0][r]) + EXP2(acc[ms][1][r]);      \
    } while (0)

    // prologue: 2 steps in flight (4 outstanding gload_lds per wave).
    STAGE(0, 0);
    STAGE(1, 1);

    int cur = 0;
    for (int t = 0; t < TSTEP - 1; ++t) {
        // stage-t landed for THIS wave once <=2 of our loads remain in flight;
        // barrier joins all waves (their slices too). Never drains to 0.
        asm volatile("s_waitcnt vmcnt(2)" ::: "memory");
        __builtin_amdgcn_s_barrier();
        __builtin_amdgcn_sched_barrier(0);
        if (t + 2 < TSTEP) {
            int nb = cur + 2; if (nb >= 3) nb -= 3;
            STAGE(t + 2, nb);   // writes the buffer read at step t-1 (barrier-safe)
        }
        COMPUTE(cur);
        ++cur; if (cur == 3) cur = 0;
    }
    // last step: only stage-24's 2 loads outstanding -> full drain.
    asm volatile("s_waitcnt vmcnt(0)" ::: "memory");
    __builtin_amdgcn_s_barrier();
    __builtin_amdgcn_sched_barrier(0);
    COMPUTE(cur);

#undef STAGE
#undef COMPUTE

    // D layout: row m = quad*4 + r (within 16-tile), col = lrow. Reduce over the
    // 16 col-lanes (lane bits 0..3), then one atomic per row per wave.
#pragma unroll
    for (int ms = 0; ms < 2; ++ms)
#pragma unroll
        for (int r = 0; r < 4; ++r) {
            float v = run[ms][r];
            v += __shfl_xor(v, 1);
            v += __shfl_xor(v, 2);
            v += __shfl_xor(v, 4);
            v += __shfl_xor(v, 8);
            if (lrow == 0)
                atomicAdd(&expsum[m0 + wv * 32 + ms * 16 + quad * 4 + r], v);
        }

    // last-block finalization (replaces k_fin): ticket after this block's atomics.
    __threadfence();
    __syncthreads();
    if (tid == 0) {
        unsigned tk = __hip_atomic_fetch_add(cnt, 1u, __ATOMIC_ACQ_REL, __HIP_MEMORY_SCOPE_AGENT);
        sdone = (tk == NBLK - 1);
    }
    __syncthreads();
    if (!sdone) return;

    float s = 0.0f;
#pragma unroll
    for (int j = 0; j < 16; ++j) {
        int idx = tid * 16 + j;   // 256*16 = 4096
        float e = __hip_atomic_load(&expsum[idx], __ATOMIC_RELAXED, __HIP_MEMORY_SCOPE_AGENT);
        if (idx < NCTR) s += LN2 * __log2f(e) - tgt[idx];
    }
#pragma unroll
    for (int off = 32; off; off >>= 1) s += __shfl_down(s, off);
    if ((tid & 63) == 0) fred[tid >> 6] = s;
    __syncthreads();
    if (tid == 0) out[0] = fred[0] + fred[1] + fred[2] + fred[3];
}

extern "C" void kernel_launch(void* const* d_in, const int* in_sizes, int n_in,
                              void* d_out, int out_size, void* d_ws, size_t ws_size,
                              hipStream_t stream) {
    const int*   tokens = (const int*)d_in[0];
    const float* emb    = (const float*)d_in[1];
    const float* W      = (const float*)d_in[2];
    float* out = (float*)d_out;
    char* ws = (char*)d_ws;
    __bf16*   Wb     = (__bf16*)ws;
    __bf16*   A      = (__bf16*)(ws + WS_A);
    float*    expsum = (float*)(ws + WS_EXPSUM);
    float*    tgt    = (float*)(ws + WS_TGT);
    unsigned* cnt    = (unsigned*)(ws + WS_CNT);

    k_setup<<<dim3(NWCONV + NCTXB), 256, 0, stream>>>(tokens, emb, W, Wb, A, tgt, expsum, cnt);
    k_gemm <<<dim3(32, SSTR), 256, 0, stream>>>(A, Wb, expsum, tgt, cnt, out);   // 1280 blocks
}